// Round 11
// baseline (686.862 us; speedup 1.0000x reference)
//
#include <hip/hip_runtime.h>

#define PN 10000
#define UN 8000
#define BN 4096
#define NGE 320000
#define NDE 320000
#define NUE 400000
#define NPUE 400000
#define INV_T 5.0f
// cumulative edge offsets: geo, tar, src, up, pu
#define E0 320000
#define E1 640000
#define E2 960000
#define E3 1360000
#define E4 1760000
#define CNT_STRIDE 48000      // per-shard counter block: geo0 tar10000 src20000 up30000 pu38000
#define RP_INTS 48008         // 5 rp arrays (48005) padded

typedef __attribute__((ext_vector_type(8))) short short8;
typedef __attribute__((ext_vector_type(4))) float f32x4;
typedef unsigned short u16;
typedef unsigned int u32;

__device__ __forceinline__ u16 f2bf(float x) {
    u32 u = __float_as_uint(x);
    return (u16)((u + 0x7FFFu + ((u >> 16) & 1u)) >> 16);
}

struct MArgs {
    const float *poi, *uemb, *wgg, *bgg, *wgs, *bgs, *wgc, *bgc, *fw, *fb;
    const float *geo_vals, *src_vals, *tar_vals, *up_vals, *pu_vals;
    const int *geo_rows, *geo_cols, *src_rows, *src_cols, *tar_rows, *tar_cols;
    const int *up_rows, *up_cols, *pu_rows, *pu_cols, *user_idx;
    float *rowsum, *colsum, *pos;
    u16 *ngb, *nsb;
    float *U0, *P0, *P1, *P2, *P3, *P4;
    int *rp_geo, *rp_tar, *rp_src, *rp_up, *rp_pu;
    int *cnt;                 // [S][CNT_STRIDE]
    int2 *geo_ent, *tar_ent, *src_ent, *up_ent, *pu_ent;
    float *out_bu, *out_fp, *out_loss;
    int smask;                // S-1 (7 or 0)
    int nshard;               // S
};

// ---------------- CSR SpMM core (int2 entries; wave per row) ----------------
// ALIAS RULES: y may alias add/avg_a/avg_b (same-thread elementwise); y must NEVER alias x.
__device__ __forceinline__ void dev_spmm(int row, int lane,
        const int* __restrict__ rp, const int2* __restrict__ ent,
        const float* __restrict__ x, const float* __restrict__ add,
        const float* __restrict__ avg_a, const float* __restrict__ avg_b,
        float* __restrict__ y, u16* __restrict__ yb, int nrows, int mode) {
    if (row >= nrows) return;
    size_t o = (size_t)row * 64 + lane;
    int s = rp[row], e = rp[row + 1];
    float acc = add ? add[o] : 0.0f;
    int p = s;
    for (; p + 4 <= e; p += 4) {
        int2 c0 = ent[p], c1 = ent[p + 1], c2 = ent[p + 2], c3 = ent[p + 3];
        float w0 = x[(size_t)c0.x * 64 + lane];
        float w1 = x[(size_t)c1.x * 64 + lane];
        float w2 = x[(size_t)c2.x * 64 + lane];
        float w3 = x[(size_t)c3.x * 64 + lane];
        acc = fmaf(__int_as_float(c0.y), w0, acc);
        acc = fmaf(__int_as_float(c1.y), w1, acc);
        acc = fmaf(__int_as_float(c2.y), w2, acc);
        acc = fmaf(__int_as_float(c3.y), w3, acc);
    }
    for (; p < e; ++p) {
        int2 c = ent[p];
        acc = fmaf(__int_as_float(c.y), x[(size_t)c.x * 64 + lane], acc);
    }
    if (mode == 0) { y[o] = acc; return; }
    float v = (avg_a[o] + avg_b[o] + acc) * (1.0f / 3.0f);
    float ss = v * v;
#pragma unroll
    for (int off = 32; off > 0; off >>= 1) ss += __shfl_xor(ss, off, 64);
    float d = fmaxf(sqrtf(ss), 1e-12f);
    float r = v / d;
    y[o] = r;
    yb[o] = f2bf(r);
}

// ---------------- single gate: out = pe * sigmoid(pe @ W + b) ----------------
__device__ void dev_gate(int u, const float* __restrict__ poi, const float* __restrict__ wg,
                         const float* __restrict__ bg, float* __restrict__ og, char* smem) {
    float* W  = (float*)smem;
    float* Bv = (float*)(smem + 16384);
    float* pe = (float*)(smem + 16384 + 256);
    int tid = threadIdx.x;
    for (int t = tid; t < 4096; t += 256) W[t] = wg[t];
    if (tid < 64) Bv[tid] = bg[tid];
    int r = tid >> 6, j = tid & 63;
    int r0 = u * 4;
    pe[r * 64 + j] = poi[(r0 + r) * 64 + j];
    __syncthreads();
    float acc = Bv[j];
#pragma unroll
    for (int k = 0; k < 64; k++) acc = fmaf(pe[r * 64 + k], W[k * 64 + j], acc);
    float pj = pe[r * 64 + j];
    og[(r0 + r) * 64 + j] = pj * (1.0f / (1.0f + __expf(-acc)));
}

// ================= D1: zero stats + sharded counters =================
__global__ void zero_kernel(MArgs A) {
    int i = blockIdx.x * 256 + threadIdx.x;
    int zn = 3 * PN + A.nshard * CNT_STRIDE;
    if (i < 3 * PN) A.rowsum[i] = 0.0f;
    else if (i < zn) A.cnt[i - 3 * PN] = 0;
}

// ================= D2: sharded hist (6875) + geo/seq gates (2x2500) =================
__global__ void hist_gates_kernel(MArgs A) {
    __shared__ __align__(16) char smem[17664];
    int u = blockIdx.x;
    if (u < 6875) {
        int e = u * 256 + threadIdx.x;
        int* base = A.cnt + (u & A.smask) * CNT_STRIDE;
        if (e < E0)      atomicAdd(&base[A.geo_rows[e]], 1);
        else if (e < E1) atomicAdd(&base[10000 + A.tar_rows[e - E0]], 1);
        else if (e < E2) atomicAdd(&base[20000 + A.src_rows[e - E1]], 1);
        else if (e < E3) atomicAdd(&base[30000 + A.up_rows[e - E2]], 1);
        else if (e < E4) atomicAdd(&base[38000 + A.pu_rows[e - E3]], 1);
    } else if (u < 6875 + 2500) {
        dev_gate(u - 6875, A.poi, A.wgg, A.bgg, A.P0, smem);          // geo_g -> P0
    } else {
        dev_gate(u - 9375, A.poi, A.wgs, A.bgs, A.P1, smem);          // seq_g -> P1
    }
}

// ================= D3: 5 scans (rp + per-shard cursor bases) =================
__global__ void scan_kernel(MArgs A) {
    __shared__ int part[256];
    int* rp; int n; int nnz; int moff;
    switch (blockIdx.x) {
        case 0: rp = A.rp_geo; n = PN; nnz = NGE;  moff = 0;     break;
        case 1: rp = A.rp_tar; n = PN; nnz = NDE;  moff = 10000; break;
        case 2: rp = A.rp_src; n = PN; nnz = NDE;  moff = 20000; break;
        case 3: rp = A.rp_up;  n = UN; nnz = NUE;  moff = 30000; break;
        default: rp = A.rp_pu; n = PN; nnz = NPUE; moff = 38000; break;
    }
    int S = A.nshard;
    int* cnt0 = A.cnt + moff;
    int tid = threadIdx.x;
    int chunk = (n + 255) >> 8;
    int base = tid * chunk;
    int s = 0;
    for (int k = 0; k < chunk; k++) {
        int i = base + k;
        if (i < n) {
            int tot = 0;
            for (int sh = 0; sh < S; sh++) tot += cnt0[sh * CNT_STRIDE + i];
            s += tot;
        }
    }
    part[tid] = s;
    __syncthreads();
    for (int off = 1; off < 256; off <<= 1) {
        int v = (tid >= off) ? part[tid - off] : 0;
        __syncthreads();
        part[tid] += v;
        __syncthreads();
    }
    int pre = (tid > 0) ? part[tid - 1] : 0;
    for (int k = 0; k < chunk; k++) {
        int i = base + k;
        if (i < n) {
            rp[i] = pre;
            for (int sh = 0; sh < S; sh++) {
                int c = cnt0[sh * CNT_STRIDE + i];
                cnt0[sh * CNT_STRIDE + i] = pre;   // becomes this shard's cursor
                pre += c;
            }
        }
    }
    if (tid == 0) rp[n] = nnz;
}

// ================= D4: scatter int2 entries with sharded cursors =================
__global__ void scatter_kernel(MArgs A) {
    int u = blockIdx.x;
    int e = u * 256 + threadIdx.x;
    int* base = A.cnt + (u & A.smask) * CNT_STRIDE;
    const int* rr; const int* kk; const float* vv; int moff; int2* en; int idx;
    if (e < E0)      { rr = A.geo_rows; kk = A.geo_cols; vv = A.geo_vals; moff = 0;     en = A.geo_ent; idx = e; }
    else if (e < E1) { rr = A.tar_rows; kk = A.tar_cols; vv = A.tar_vals; moff = 10000; en = A.tar_ent; idx = e - E0; }
    else if (e < E2) { rr = A.src_rows; kk = A.src_cols; vv = A.src_vals; moff = 20000; en = A.src_ent; idx = e - E1; }
    else if (e < E3) { rr = A.up_rows;  kk = A.up_cols;  vv = A.up_vals;  moff = 30000; en = A.up_ent;  idx = e - E2; }
    else if (e < E4) { rr = A.pu_rows;  kk = A.pu_cols;  vv = A.pu_vals;  moff = 38000; en = A.pu_ent;  idx = e - E3; }
    else return;
    int p = atomicAdd(&base[moff + rr[idx]], 1);
    en[p] = make_int2(kk[idx], __float_as_int(vv[idx]));
}

// ================= D5-D8, D12: SpMM phases =================
// step 0: geo1 (x1_g=A*g+g: P0->P3) || tar1 (m1=T*sg: P1->P4)          grid 5000
// step 1: geo2fin (x2=A*x1+x1; ng->P0,ngb) || s1 (x1_s=S*m1+sg: ->P2)  grid 5000
// step 2: tar2 (m2=T*x1_s: P2->P3) || gate_col (->P4)                  grid 5000
// step 3: s2fin (x2=S*m2+x1_s; ns->P1,nsb)                             grid 2500
// step 4: users_struct = up * fusion(P3) -> U0                         grid 2000
__global__ __launch_bounds__(256) void spmm_step_kernel(MArgs A, int step) {
    __shared__ __align__(16) char smem[17664];
    int tid = threadIdx.x;
    int lane = tid & 63, w = tid >> 6;
    int u = blockIdx.x;
    if (step == 0) {
        if (u < 2500) dev_spmm(u * 4 + w, lane, A.rp_geo, A.geo_ent,
                               A.P0, A.P0, nullptr, nullptr, A.P3, nullptr, PN, 0);
        else dev_spmm((u - 2500) * 4 + w, lane, A.rp_tar, A.tar_ent,
                      A.P1, nullptr, nullptr, nullptr, A.P4, nullptr, PN, 0);
    } else if (step == 1) {
        if (u < 2500) dev_spmm(u * 4 + w, lane, A.rp_geo, A.geo_ent,
                               A.P3, A.P3, A.P0, A.P3, A.P0, A.ngb, PN, 1);
        else dev_spmm((u - 2500) * 4 + w, lane, A.rp_src, A.src_ent,
                      A.P4, A.P1, nullptr, nullptr, A.P2, nullptr, PN, 0);
    } else if (step == 2) {
        if (u < 2500) dev_spmm(u * 4 + w, lane, A.rp_tar, A.tar_ent,
                               A.P2, nullptr, nullptr, nullptr, A.P3, nullptr, PN, 0);
        else dev_gate(u - 2500, A.poi, A.wgc, A.bgc, A.P4, smem);
    } else if (step == 3) {
        dev_spmm(u * 4 + w, lane, A.rp_src, A.src_ent,
                 A.P3, A.P2, A.P1, A.P2, A.P1, A.nsb, PN, 1);
    } else {
        dev_spmm(u * 4 + w, lane, A.rp_up, A.up_ent,
                 A.P3, nullptr, nullptr, nullptr, A.U0, nullptr, UN, 0);
    }
}

// ================= D9: MFMA InfoNCE (standalone — ngb/nsb stay L2-resident) =================
__global__ __launch_bounds__(256) void infonce_kernel(MArgs A) {
    __shared__ __align__(16) char smraw[36864];
    u16* Al = (u16*)smraw;
    u16* Bl = (u16*)(smraw + 18432);
    float* red = (float*)smraw;      // reused after frags cached
    int tid = threadIdx.x;
    int bx = blockIdx.x % 79, by = blockIdx.x / 79;
    int i0 = bx * 128, j0 = by * 128;
    const uint4 zero4 = make_uint4(0, 0, 0, 0);
    for (int u = tid; u < 1024; u += 256) {
        int row = u >> 3, ch = u & 7;
        int ga = i0 + row, gb = j0 + row;
        uint4 va = (ga < PN) ? ((const uint4*)A.ngb)[(size_t)ga * 8 + ch] : zero4;
        uint4 vb = (gb < PN) ? ((const uint4*)A.nsb)[(size_t)gb * 8 + ch] : zero4;
        ((uint4*)Al)[row * 9 + ch] = va;
        ((uint4*)Bl)[row * 9 + ch] = vb;
    }
    __syncthreads();
    int wv = tid >> 6, lane = tid & 63;
    int wr = (wv & 1) * 64;
    int wc = (wv >> 1) * 64;
    int quad = lane >> 4, l15 = lane & 15;

    short8 af[4][2], bf[4][2];
#pragma unroll
    for (int tt = 0; tt < 4; tt++)
#pragma unroll
        for (int ks = 0; ks < 2; ks++) {
            af[tt][ks] = *(const short8*)&Al[(wr + tt * 16 + l15) * 72 + ks * 32 + quad * 8];
            bf[tt][ks] = *(const short8*)&Bl[(wc + tt * 16 + l15) * 72 + ks * 32 + quad * 8];
        }
    __syncthreads();

    f32x4 acc[4][4];
#pragma unroll
    for (int rt = 0; rt < 4; rt++)
#pragma unroll
        for (int ct = 0; ct < 4; ct++) {
            f32x4 c = {0.f, 0.f, 0.f, 0.f};
            c = __builtin_amdgcn_mfma_f32_16x16x32_bf16(af[rt][0], bf[ct][0], c, 0, 0, 0);
            c = __builtin_amdgcn_mfma_f32_16x16x32_bf16(af[rt][1], bf[ct][1], c, 0, 0, 0);
            acc[rt][ct] = c;
        }

    float rs[4][4];
#pragma unroll
    for (int rt = 0; rt < 4; rt++)
#pragma unroll
        for (int g = 0; g < 4; g++) rs[rt][g] = 0.f;
    float cs[4] = {0.f, 0.f, 0.f, 0.f};

    bool interior = (i0 + 128 <= PN) && (j0 + 128 <= PN) && (i0 != j0);
    if (interior) {
#pragma unroll
        for (int rt = 0; rt < 4; rt++)
#pragma unroll
            for (int ct = 0; ct < 4; ct++) {
                float csum = 0.f;
#pragma unroll
                for (int g = 0; g < 4; g++) {
                    float e = __expf(acc[rt][ct][g] * INV_T);
                    rs[rt][g] += e;
                    csum += e;
                }
                cs[ct] += csum;
            }
    } else {
#pragma unroll
        for (int rt = 0; rt < 4; rt++) {
            int ibase = i0 + wr + rt * 16 + quad * 4;
#pragma unroll
            for (int ct = 0; ct < 4; ct++) {
                int j = j0 + wc + ct * 16 + l15;
                bool jv = (j < PN);
                float csum = 0.f;
#pragma unroll
                for (int g = 0; g < 4; g++) {
                    int i = ibase + g;
                    float e = 0.f;
                    if (jv && i < PN) {
                        e = __expf(acc[rt][ct][g] * INV_T);
                        if (i == j) A.pos[i] = e;
                    }
                    rs[rt][g] += e;
                    csum += e;
                }
                cs[ct] += csum;
            }
        }
    }
#pragma unroll
    for (int off = 16; off <= 32; off <<= 1)
#pragma unroll
        for (int ct = 0; ct < 4; ct++) cs[ct] += __shfl_xor(cs[ct], off, 64);
    if (quad == 0) {
#pragma unroll
        for (int ct = 0; ct < 4; ct++) {
            int j = j0 + wc + ct * 16 + l15;
            if (j < PN) atomicAdd(&A.colsum[j], cs[ct]);
        }
    }
    int slot = (wv >> 1) * 16 + l15;
#pragma unroll
    for (int rt = 0; rt < 4; rt++)
#pragma unroll
        for (int g = 0; g < 4; g++) {
            int rl = wr + rt * 16 + quad * 4 + g;
            red[slot * 131 + rl] = rs[rt][g];
        }
    __syncthreads();
    if (tid < 128) {
        float sum = 0.f;
#pragma unroll
        for (int s2 = 0; s2 < 32; s2++) sum += red[s2 * 131 + tid];
        int i = i0 + tid;
        if (i < PN) atomicAdd(&A.rowsum[i], sum);
    }
}

// ================= D10: spmm3(up) + fuse_users =================
__global__ void fuse_kernel(MArgs A) {
    __shared__ float msg[4][448];
    int tid = threadIdx.x, lane = tid & 63, r = tid >> 6;
    int row = blockIdx.x * 4 + r;
    float a0 = 0.f, a1 = 0.f, a2 = 0.f;
    {
        int s = A.rp_up[row], e = A.rp_up[row + 1];
        for (int p = s; p < e; ++p) {
            int2 c = A.up_ent[p];
            float v = __int_as_float(c.y);
            size_t o = (size_t)c.x * 64 + lane;
            a0 = fmaf(v, A.P0[o], a0);
            a1 = fmaf(v, A.P1[o], a1);
            a2 = fmaf(v, A.P4[o], a2);
        }
    }
    msg[r][0 * 64 + lane] = a0;
    msg[r][1 * 64 + lane] = a1;
    msg[r][2 * 64 + lane] = a2;
    msg[r][3 * 64 + lane] = a0 * a1;
    msg[r][4 * 64 + lane] = a0 * a2;
    msg[r][5 * 64 + lane] = a1 * a2;
    msg[r][6 * 64 + lane] = a0 * a1 * a2;
    __syncthreads();
    float acc = A.fb[lane];
#pragma unroll 8
    for (int k = 0; k < 448; k++) acc = fmaf(msg[r][k], A.fw[k * 64 + lane], acc);
    size_t o = (size_t)row * 64 + lane;
    float uu = A.uemb[o];
    A.U0[o] = acc + uu + acc * uu;
}

// ================= D11: pu spmm + col_g add + fusion_out =================
__global__ void puout_kernel(MArgs A) {
    int lane = threadIdx.x & 63;
    int row = blockIdx.x * 4 + (threadIdx.x >> 6);
    size_t o = (size_t)row * 64 + lane;
    float acc = A.P4[o];          // col_g
    int s = A.rp_pu[row], e = A.rp_pu[row + 1];
    int p = s;
    for (; p + 4 <= e; p += 4) {
        int2 c0 = A.pu_ent[p], c1 = A.pu_ent[p + 1], c2 = A.pu_ent[p + 2], c3 = A.pu_ent[p + 3];
        float w0 = A.U0[(size_t)c0.x * 64 + lane];
        float w1 = A.U0[(size_t)c1.x * 64 + lane];
        float w2 = A.U0[(size_t)c2.x * 64 + lane];
        float w3 = A.U0[(size_t)c3.x * 64 + lane];
        acc = fmaf(__int_as_float(c0.y), w0, acc);
        acc = fmaf(__int_as_float(c1.y), w1, acc);
        acc = fmaf(__int_as_float(c2.y), w2, acc);
        acc = fmaf(__int_as_float(c3.y), w3, acc);
    }
    for (; p < e; ++p) {
        int2 c = A.pu_ent[p];
        acc = fmaf(__int_as_float(c.y), A.U0[(size_t)c.x * 64 + lane], acc);
    }
    float ss = acc * acc;
#pragma unroll
    for (int off = 32; off > 0; off >>= 1) ss += __shfl_xor(ss, off, 64);
    float d = fmaxf(sqrtf(ss), 1e-12f);
    float f = acc / d + A.P0[o] + A.P1[o];
    A.P3[o] = f;
    A.out_fp[o] = f;
}

// ================= D13: batch_users + loss =================
__global__ void batch_loss_kernel(MArgs A) {
    __shared__ float red[256];
    int tid = threadIdx.x;
    if ((int)blockIdx.x < 1024) {
        int lane = tid & 63;
        int b = blockIdx.x * 4 + (tid >> 6);
        int r = A.user_idx[b];
        float v = A.U0[(size_t)r * 64 + lane];
        float s = v * v;
#pragma unroll
        for (int off = 32; off > 0; off >>= 1) s += __shfl_xor(s, off, 64);
        float d = fmaxf(sqrtf(s), 1e-12f);
        A.out_bu[(size_t)b * 64 + lane] = v / d;
        return;
    }
    float acc = 0.0f;
    for (int i = tid; i < PN; i += 256) {
        float p = A.pos[i];
        acc += -logf(p / (A.rowsum[i] + 1e-8f) + 1e-8f);
        acc += -logf(p / (A.colsum[i] + 1e-8f) + 1e-8f);
    }
    red[tid] = acc;
    __syncthreads();
    for (int s = 128; s > 0; s >>= 1) {
        if (tid < s) red[tid] += red[tid + s];
        __syncthreads();
    }
    if (tid == 0) A.out_loss[0] = 0.5f * red[0] / (float)PN;
}

extern "C" void kernel_launch(void* const* d_in, const int* in_sizes, int n_in,
                              void* d_out, int out_size, void* d_ws, size_t ws_size,
                              hipStream_t stream) {
    (void)in_sizes; (void)n_in; (void)out_size;
    const int PD = PN * 64, UD = UN * 64;

    MArgs A;
    A.poi  = (const float*)d_in[0];
    A.uemb = (const float*)d_in[1];
    A.wgg  = (const float*)d_in[2];
    A.bgg  = (const float*)d_in[3];
    A.wgs  = (const float*)d_in[4];
    A.bgs  = (const float*)d_in[5];
    A.wgc  = (const float*)d_in[6];
    A.bgc  = (const float*)d_in[7];
    A.fw   = (const float*)d_in[8];
    A.fb   = (const float*)d_in[9];
    A.geo_vals = (const float*)d_in[10];
    A.src_vals = (const float*)d_in[11];
    A.tar_vals = (const float*)d_in[12];
    A.up_vals  = (const float*)d_in[13];
    A.pu_vals  = (const float*)d_in[14];
    A.geo_rows = (const int*)d_in[15];
    A.geo_cols = (const int*)d_in[16];
    A.src_rows = (const int*)d_in[17];
    A.src_cols = (const int*)d_in[18];
    A.tar_rows = (const int*)d_in[19];
    A.tar_cols = (const int*)d_in[20];
    A.up_rows  = (const int*)d_in[21];
    A.up_cols  = (const int*)d_in[22];
    A.pu_rows  = (const int*)d_in[23];
    A.pu_cols  = (const int*)d_in[24];
    A.user_idx = (const int*)d_in[25];

    float* F = (float*)d_ws;
    A.rowsum = F;
    A.colsum = A.rowsum + PN;
    A.pos    = A.colsum + PN;
    A.ngb    = (u16*)(F + 3 * PN);
    A.nsb    = A.ngb + PD;
    A.U0     = F + 3 * PN + PD;
    A.P0     = A.U0 + UD;
    A.P1     = A.P0 + PD;
    A.P2     = A.P1 + PD;
    A.P3     = A.P2 + PD;
    A.P4     = A.P3 + PD;
    int* M   = (int*)(A.P4 + PD);
    A.rp_geo = M;
    A.rp_tar = A.rp_geo + PN + 1;
    A.rp_src = A.rp_tar + PN + 1;
    A.rp_up  = A.rp_src + PN + 1;
    A.rp_pu  = A.rp_up + UN + 1;
    A.cnt    = M + RP_INTS;

    // pick shard count by workspace budget (deterministic across calls)
    size_t fixed_bytes = ((size_t)(3 * PN + PD + UD + 5 * PD) + RP_INTS) * 4
                       + 2ull * (NGE + NDE + NDE + NUE + NPUE) * 8 / 8 * 8;  // entries added below
    size_t ent_bytes = (size_t)(NGE + NDE + NDE + NUE + NPUE) * 8;
    int S = 8;
    {
        size_t need8 = ((size_t)(3 * PN + PD + UD + 5 * PD) + RP_INTS + 8 * CNT_STRIDE) * 4 + ent_bytes;
        if (ws_size < need8) S = 1;
    }
    (void)fixed_bytes;
    A.nshard = S;
    A.smask  = S - 1;
    int2* ents = (int2*)(A.cnt + S * CNT_STRIDE);
    A.geo_ent = ents;
    A.tar_ent = A.geo_ent + NGE;
    A.src_ent = A.tar_ent + NDE;
    A.up_ent  = A.src_ent + NDE;
    A.pu_ent  = A.up_ent + NUE;

    A.out_bu = (float*)d_out;
    A.out_fp = A.out_bu + (size_t)BN * 64;
    A.out_loss = A.out_fp + (size_t)PN * 64;

    const int NTOTB = (E4 + 255) / 256;            // 6875
    const int ZB = (3 * PN + S * CNT_STRIDE + 255) / 256;

    // D1: zero stats + sharded counters
    zero_kernel<<<ZB, 256, 0, stream>>>(A);
    // D2: sharded hist + geo/seq gates
    hist_gates_kernel<<<NTOTB + 5000, 256, 0, stream>>>(A);
    // D3: scans (rp + shard cursor bases)
    scan_kernel<<<5, 256, 0, stream>>>(A);
    // D4: scatter int2 with sharded cursors
    scatter_kernel<<<NTOTB, 256, 0, stream>>>(A);
    // D5: geo1 || tar1
    spmm_step_kernel<<<5000, 256, 0, stream>>>(A, 0);
    // D6: geo2-final (ng) || s1
    spmm_step_kernel<<<5000, 256, 0, stream>>>(A, 1);
    // D7: tar2 || gate_col
    spmm_step_kernel<<<5000, 256, 0, stream>>>(A, 2);
    // D8: s2-final (ns)
    spmm_step_kernel<<<2500, 256, 0, stream>>>(A, 3);
    // D9: InfoNCE (MFMA) — standalone
    infonce_kernel<<<6241, 256, 0, stream>>>(A);
    // D10: spmm3(up) + fuse_users
    fuse_kernel<<<2000, 256, 0, stream>>>(A);
    // D11: pu spmm + fusion_out
    puout_kernel<<<2500, 256, 0, stream>>>(A);
    // D12: users_struct = up * fusion
    spmm_step_kernel<<<2000, 256, 0, stream>>>(A, 4);
    // D13: batch_users + loss
    batch_loss_kernel<<<1025, 256, 0, stream>>>(A);
}

// Round 12
// 621.790 us; speedup vs baseline: 1.1047x; 1.1047x over previous
//
#include <hip/hip_runtime.h>

#define PN 10000
#define UN 8000
#define BN 4096
#define NGE 320000
#define NDE 320000
#define NUE 400000
#define NPUE 400000
#define INV_T 5.0f
// cumulative edge offsets: geo, tar, src, up, pu
#define E0 320000
#define E1 640000
#define E2 960000
#define E3 1360000
#define E4 1760000
#define CNT_STRIDE 48000      // per-shard counter block: geo0 tar10000 src20000 up30000 pu38000
#define RP_INTS 48008         // 5 rp arrays (48005) padded

typedef __attribute__((ext_vector_type(8))) short short8;
typedef __attribute__((ext_vector_type(4))) float f32x4;
typedef unsigned short u16;
typedef unsigned int u32;

__device__ __forceinline__ u16 f2bf(float x) {
    u32 u = __float_as_uint(x);
    return (u16)((u + 0x7FFFu + ((u >> 16) & 1u)) >> 16);
}

struct MArgs {
    const float *poi, *uemb, *wgg, *bgg, *wgs, *bgs, *wgc, *bgc, *fw, *fb;
    const float *geo_vals, *src_vals, *tar_vals, *up_vals, *pu_vals;
    const int *geo_rows, *geo_cols, *src_rows, *src_cols, *tar_rows, *tar_cols;
    const int *up_rows, *up_cols, *pu_rows, *pu_cols, *user_idx;
    float *rowsum, *colsum, *pos;
    u16 *ngb, *nsb;
    float *U0, *P0, *P1, *P2, *P3, *P4;
    int *rp_geo, *rp_tar, *rp_src, *rp_up, *rp_pu;
    int *cnt;                 // [S][CNT_STRIDE]
    int2 *geo_ent, *tar_ent, *src_ent, *up_ent, *pu_ent;
    float *out_bu, *out_fp, *out_loss;
    int smask;                // S-1 (7 or 0)
    int nshard;               // S
};

// ---------------- CSR SpMM core (int2 entries; wave per row) ----------------
// ALIAS RULES: y may alias add/avg_a/avg_b (same-thread elementwise); y must NEVER alias x.
__device__ __forceinline__ void dev_spmm(int row, int lane,
        const int* __restrict__ rp, const int2* __restrict__ ent,
        const float* __restrict__ x, const float* __restrict__ add,
        const float* __restrict__ avg_a, const float* __restrict__ avg_b,
        float* __restrict__ y, u16* __restrict__ yb, int nrows, int mode) {
    if (row >= nrows) return;
    size_t o = (size_t)row * 64 + lane;
    int s = rp[row], e = rp[row + 1];
    float acc = add ? add[o] : 0.0f;
    int p = s;
    for (; p + 4 <= e; p += 4) {
        int2 c0 = ent[p], c1 = ent[p + 1], c2 = ent[p + 2], c3 = ent[p + 3];
        float w0 = x[(size_t)c0.x * 64 + lane];
        float w1 = x[(size_t)c1.x * 64 + lane];
        float w2 = x[(size_t)c2.x * 64 + lane];
        float w3 = x[(size_t)c3.x * 64 + lane];
        acc = fmaf(__int_as_float(c0.y), w0, acc);
        acc = fmaf(__int_as_float(c1.y), w1, acc);
        acc = fmaf(__int_as_float(c2.y), w2, acc);
        acc = fmaf(__int_as_float(c3.y), w3, acc);
    }
    for (; p < e; ++p) {
        int2 c = ent[p];
        acc = fmaf(__int_as_float(c.y), x[(size_t)c.x * 64 + lane], acc);
    }
    if (mode == 0) { y[o] = acc; return; }
    float v = (avg_a[o] + avg_b[o] + acc) * (1.0f / 3.0f);
    float ss = v * v;
#pragma unroll
    for (int off = 32; off > 0; off >>= 1) ss += __shfl_xor(ss, off, 64);
    float d = fmaxf(sqrtf(ss), 1e-12f);
    float r = v / d;
    y[o] = r;
    yb[o] = f2bf(r);
}

// ---------------- single gate: out = pe * sigmoid(pe @ W + b) ----------------
__device__ void dev_gate(int u, const float* __restrict__ poi, const float* __restrict__ wg,
                         const float* __restrict__ bg, float* __restrict__ og, char* smem) {
    float* W  = (float*)smem;
    float* Bv = (float*)(smem + 16384);
    float* pe = (float*)(smem + 16384 + 256);
    int tid = threadIdx.x;
    for (int t = tid; t < 4096; t += 256) W[t] = wg[t];
    if (tid < 64) Bv[tid] = bg[tid];
    int r = tid >> 6, j = tid & 63;
    int r0 = u * 4;
    pe[r * 64 + j] = poi[(r0 + r) * 64 + j];
    __syncthreads();
    float acc = Bv[j];
#pragma unroll
    for (int k = 0; k < 64; k++) acc = fmaf(pe[r * 64 + k], W[k * 64 + j], acc);
    float pj = pe[r * 64 + j];
    og[(r0 + r) * 64 + j] = pj * (1.0f / (1.0f + __expf(-acc)));
}

// ================= D1: zero stats + sharded counters =================
__global__ void zero_kernel(MArgs A) {
    int i = blockIdx.x * 256 + threadIdx.x;
    int zn = 3 * PN + A.nshard * CNT_STRIDE;
    if (i < 3 * PN) A.rowsum[i] = 0.0f;
    else if (i < zn) A.cnt[i - 3 * PN] = 0;
}

// ================= D2: sharded hist (6875) + geo/seq gates (2x2500) =================
__global__ void hist_gates_kernel(MArgs A) {
    __shared__ __align__(16) char smem[17664];
    int u = blockIdx.x;
    if (u < 6875) {
        int e = u * 256 + threadIdx.x;
        int* base = A.cnt + (u & A.smask) * CNT_STRIDE;
        if (e < E0)      atomicAdd(&base[A.geo_rows[e]], 1);
        else if (e < E1) atomicAdd(&base[10000 + A.tar_rows[e - E0]], 1);
        else if (e < E2) atomicAdd(&base[20000 + A.src_rows[e - E1]], 1);
        else if (e < E3) atomicAdd(&base[30000 + A.up_rows[e - E2]], 1);
        else if (e < E4) atomicAdd(&base[38000 + A.pu_rows[e - E3]], 1);
    } else if (u < 6875 + 2500) {
        dev_gate(u - 6875, A.poi, A.wgg, A.bgg, A.P0, smem);          // geo_g -> P0
    } else {
        dev_gate(u - 9375, A.poi, A.wgs, A.bgs, A.P1, smem);          // seq_g -> P1
    }
}

// ================= D3: 5 scans, 1024 threads, batched shard loads =================
__global__ __launch_bounds__(1024) void scan_kernel(MArgs A) {
    __shared__ int part[1024];
    int* rp; int n; int nnz; int moff;
    switch (blockIdx.x) {
        case 0: rp = A.rp_geo; n = PN; nnz = NGE;  moff = 0;     break;
        case 1: rp = A.rp_tar; n = PN; nnz = NDE;  moff = 10000; break;
        case 2: rp = A.rp_src; n = PN; nnz = NDE;  moff = 20000; break;
        case 3: rp = A.rp_up;  n = UN; nnz = NUE;  moff = 30000; break;
        default: rp = A.rp_pu; n = PN; nnz = NPUE; moff = 38000; break;
    }
    int S = A.nshard;
    int* cnt0 = A.cnt + moff;
    int tid = threadIdx.x;
    int chunk = (n + 1023) >> 10;          // 10 (P-dim) or 8 (U-dim)
    int base = tid * chunk;
    int s = 0;
    if (S == 8) {
        for (int k = 0; k < chunk; k++) {
            int i = base + k;
            if (i < n) {
                int c[8];
#pragma unroll
                for (int sh = 0; sh < 8; sh++) c[sh] = cnt0[sh * CNT_STRIDE + i];
#pragma unroll
                for (int sh = 0; sh < 8; sh++) s += c[sh];
            }
        }
    } else {
        for (int k = 0; k < chunk; k++) {
            int i = base + k;
            if (i < n) s += cnt0[i];
        }
    }
    part[tid] = s;
    __syncthreads();
    for (int off = 1; off < 1024; off <<= 1) {
        int v = (tid >= off) ? part[tid - off] : 0;
        __syncthreads();
        part[tid] += v;
        __syncthreads();
    }
    int pre = (tid > 0) ? part[tid - 1] : 0;
    if (S == 8) {
        for (int k = 0; k < chunk; k++) {
            int i = base + k;
            if (i < n) {
                int c[8];
#pragma unroll
                for (int sh = 0; sh < 8; sh++) c[sh] = cnt0[sh * CNT_STRIDE + i];
                rp[i] = pre;
#pragma unroll
                for (int sh = 0; sh < 8; sh++) {
                    cnt0[sh * CNT_STRIDE + i] = pre;   // shard cursor base
                    pre += c[sh];
                }
            }
        }
    } else {
        for (int k = 0; k < chunk; k++) {
            int i = base + k;
            if (i < n) {
                int c = cnt0[i];
                rp[i] = pre;
                cnt0[i] = pre;
                pre += c;
            }
        }
    }
    if (tid == 0) rp[n] = nnz;
}

// ================= D4: scatter int2 entries with sharded cursors =================
__global__ void scatter_kernel(MArgs A) {
    int u = blockIdx.x;
    int e = u * 256 + threadIdx.x;
    int* base = A.cnt + (u & A.smask) * CNT_STRIDE;
    const int* rr; const int* kk; const float* vv; int moff; int2* en; int idx;
    if (e < E0)      { rr = A.geo_rows; kk = A.geo_cols; vv = A.geo_vals; moff = 0;     en = A.geo_ent; idx = e; }
    else if (e < E1) { rr = A.tar_rows; kk = A.tar_cols; vv = A.tar_vals; moff = 10000; en = A.tar_ent; idx = e - E0; }
    else if (e < E2) { rr = A.src_rows; kk = A.src_cols; vv = A.src_vals; moff = 20000; en = A.src_ent; idx = e - E1; }
    else if (e < E3) { rr = A.up_rows;  kk = A.up_cols;  vv = A.up_vals;  moff = 30000; en = A.up_ent;  idx = e - E2; }
    else if (e < E4) { rr = A.pu_rows;  kk = A.pu_cols;  vv = A.pu_vals;  moff = 38000; en = A.pu_ent;  idx = e - E3; }
    else return;
    int p = atomicAdd(&base[moff + rr[idx]], 1);
    en[p] = make_int2(kk[idx], __float_as_int(vv[idx]));
}

// ================= D5-D8, D12: SpMM phases =================
// step 0: geo1 (x1_g=A*g+g: P0->P3) || tar1 (m1=T*sg: P1->P4)          grid 5000
// step 1: geo2fin (x2=A*x1+x1; ng->P0,ngb) || s1 (x1_s=S*m1+sg: ->P2)  grid 5000
// step 2: tar2 (m2=T*x1_s: P2->P3) || gate_col (->P4)                  grid 5000
// step 3: s2fin (x2=S*m2+x1_s; ns->P1,nsb)                             grid 2500
// step 4: users_struct = up * fusion(P3) -> U0                         grid 2000
__global__ __launch_bounds__(256) void spmm_step_kernel(MArgs A, int step) {
    __shared__ __align__(16) char smem[17664];
    int tid = threadIdx.x;
    int lane = tid & 63, w = tid >> 6;
    int u = blockIdx.x;
    if (step == 0) {
        if (u < 2500) dev_spmm(u * 4 + w, lane, A.rp_geo, A.geo_ent,
                               A.P0, A.P0, nullptr, nullptr, A.P3, nullptr, PN, 0);
        else dev_spmm((u - 2500) * 4 + w, lane, A.rp_tar, A.tar_ent,
                      A.P1, nullptr, nullptr, nullptr, A.P4, nullptr, PN, 0);
    } else if (step == 1) {
        if (u < 2500) dev_spmm(u * 4 + w, lane, A.rp_geo, A.geo_ent,
                               A.P3, A.P3, A.P0, A.P3, A.P0, A.ngb, PN, 1);
        else dev_spmm((u - 2500) * 4 + w, lane, A.rp_src, A.src_ent,
                      A.P4, A.P1, nullptr, nullptr, A.P2, nullptr, PN, 0);
    } else if (step == 2) {
        if (u < 2500) dev_spmm(u * 4 + w, lane, A.rp_tar, A.tar_ent,
                               A.P2, nullptr, nullptr, nullptr, A.P3, nullptr, PN, 0);
        else dev_gate(u - 2500, A.poi, A.wgc, A.bgc, A.P4, smem);
    } else if (step == 3) {
        dev_spmm(u * 4 + w, lane, A.rp_src, A.src_ent,
                 A.P3, A.P2, A.P1, A.P2, A.P1, A.nsb, PN, 1);
    } else {
        dev_spmm(u * 4 + w, lane, A.rp_up, A.up_ent,
                 A.P3, nullptr, nullptr, nullptr, A.U0, nullptr, UN, 0);
    }
}

// ================= D9: MFMA InfoNCE (standalone — ngb/nsb stay L2-resident) =================
__global__ __launch_bounds__(256) void infonce_kernel(MArgs A) {
    __shared__ __align__(16) char smraw[36864];
    u16* Al = (u16*)smraw;
    u16* Bl = (u16*)(smraw + 18432);
    float* red = (float*)smraw;      // reused after frags cached
    int tid = threadIdx.x;
    int bx = blockIdx.x % 79, by = blockIdx.x / 79;
    int i0 = bx * 128, j0 = by * 128;
    const uint4 zero4 = make_uint4(0, 0, 0, 0);
    for (int u = tid; u < 1024; u += 256) {
        int row = u >> 3, ch = u & 7;
        int ga = i0 + row, gb = j0 + row;
        uint4 va = (ga < PN) ? ((const uint4*)A.ngb)[(size_t)ga * 8 + ch] : zero4;
        uint4 vb = (gb < PN) ? ((const uint4*)A.nsb)[(size_t)gb * 8 + ch] : zero4;
        ((uint4*)Al)[row * 9 + ch] = va;
        ((uint4*)Bl)[row * 9 + ch] = vb;
    }
    __syncthreads();
    int wv = tid >> 6, lane = tid & 63;
    int wr = (wv & 1) * 64;
    int wc = (wv >> 1) * 64;
    int quad = lane >> 4, l15 = lane & 15;

    short8 af[4][2], bf[4][2];
#pragma unroll
    for (int tt = 0; tt < 4; tt++)
#pragma unroll
        for (int ks = 0; ks < 2; ks++) {
            af[tt][ks] = *(const short8*)&Al[(wr + tt * 16 + l15) * 72 + ks * 32 + quad * 8];
            bf[tt][ks] = *(const short8*)&Bl[(wc + tt * 16 + l15) * 72 + ks * 32 + quad * 8];
        }
    __syncthreads();

    f32x4 acc[4][4];
#pragma unroll
    for (int rt = 0; rt < 4; rt++)
#pragma unroll
        for (int ct = 0; ct < 4; ct++) {
            f32x4 c = {0.f, 0.f, 0.f, 0.f};
            c = __builtin_amdgcn_mfma_f32_16x16x32_bf16(af[rt][0], bf[ct][0], c, 0, 0, 0);
            c = __builtin_amdgcn_mfma_f32_16x16x32_bf16(af[rt][1], bf[ct][1], c, 0, 0, 0);
            acc[rt][ct] = c;
        }

    float rs[4][4];
#pragma unroll
    for (int rt = 0; rt < 4; rt++)
#pragma unroll
        for (int g = 0; g < 4; g++) rs[rt][g] = 0.f;
    float cs[4] = {0.f, 0.f, 0.f, 0.f};

    bool interior = (i0 + 128 <= PN) && (j0 + 128 <= PN) && (i0 != j0);
    if (interior) {
#pragma unroll
        for (int rt = 0; rt < 4; rt++)
#pragma unroll
            for (int ct = 0; ct < 4; ct++) {
                float csum = 0.f;
#pragma unroll
                for (int g = 0; g < 4; g++) {
                    float e = __expf(acc[rt][ct][g] * INV_T);
                    rs[rt][g] += e;
                    csum += e;
                }
                cs[ct] += csum;
            }
    } else {
#pragma unroll
        for (int rt = 0; rt < 4; rt++) {
            int ibase = i0 + wr + rt * 16 + quad * 4;
#pragma unroll
            for (int ct = 0; ct < 4; ct++) {
                int j = j0 + wc + ct * 16 + l15;
                bool jv = (j < PN);
                float csum = 0.f;
#pragma unroll
                for (int g = 0; g < 4; g++) {
                    int i = ibase + g;
                    float e = 0.f;
                    if (jv && i < PN) {
                        e = __expf(acc[rt][ct][g] * INV_T);
                        if (i == j) A.pos[i] = e;
                    }
                    rs[rt][g] += e;
                    csum += e;
                }
                cs[ct] += csum;
            }
        }
    }
#pragma unroll
    for (int off = 16; off <= 32; off <<= 1)
#pragma unroll
        for (int ct = 0; ct < 4; ct++) cs[ct] += __shfl_xor(cs[ct], off, 64);
    if (quad == 0) {
#pragma unroll
        for (int ct = 0; ct < 4; ct++) {
            int j = j0 + wc + ct * 16 + l15;
            if (j < PN) atomicAdd(&A.colsum[j], cs[ct]);
        }
    }
    int slot = (wv >> 1) * 16 + l15;
#pragma unroll
    for (int rt = 0; rt < 4; rt++)
#pragma unroll
        for (int g = 0; g < 4; g++) {
            int rl = wr + rt * 16 + quad * 4 + g;
            red[slot * 131 + rl] = rs[rt][g];
        }
    __syncthreads();
    if (tid < 128) {
        float sum = 0.f;
#pragma unroll
        for (int s2 = 0; s2 < 32; s2++) sum += red[s2 * 131 + tid];
        int i = i0 + tid;
        if (i < PN) atomicAdd(&A.rowsum[i], sum);
    }
}

// ================= D10: spmm3(up) + fuse_users =================
__global__ void fuse_kernel(MArgs A) {
    __shared__ float msg[4][448];
    int tid = threadIdx.x, lane = tid & 63, r = tid >> 6;
    int row = blockIdx.x * 4 + r;
    float a0 = 0.f, a1 = 0.f, a2 = 0.f;
    {
        int s = A.rp_up[row], e = A.rp_up[row + 1];
        for (int p = s; p < e; ++p) {
            int2 c = A.up_ent[p];
            float v = __int_as_float(c.y);
            size_t o = (size_t)c.x * 64 + lane;
            a0 = fmaf(v, A.P0[o], a0);
            a1 = fmaf(v, A.P1[o], a1);
            a2 = fmaf(v, A.P4[o], a2);
        }
    }
    msg[r][0 * 64 + lane] = a0;
    msg[r][1 * 64 + lane] = a1;
    msg[r][2 * 64 + lane] = a2;
    msg[r][3 * 64 + lane] = a0 * a1;
    msg[r][4 * 64 + lane] = a0 * a2;
    msg[r][5 * 64 + lane] = a1 * a2;
    msg[r][6 * 64 + lane] = a0 * a1 * a2;
    __syncthreads();
    float acc = A.fb[lane];
#pragma unroll 8
    for (int k = 0; k < 448; k++) acc = fmaf(msg[r][k], A.fw[k * 64 + lane], acc);
    size_t o = (size_t)row * 64 + lane;
    float uu = A.uemb[o];
    A.U0[o] = acc + uu + acc * uu;
}

// ================= D11: pu spmm + col_g add + fusion_out =================
__global__ void puout_kernel(MArgs A) {
    int lane = threadIdx.x & 63;
    int row = blockIdx.x * 4 + (threadIdx.x >> 6);
    size_t o = (size_t)row * 64 + lane;
    float acc = A.P4[o];          // col_g
    int s = A.rp_pu[row], e = A.rp_pu[row + 1];
    int p = s;
    for (; p + 4 <= e; p += 4) {
        int2 c0 = A.pu_ent[p], c1 = A.pu_ent[p + 1], c2 = A.pu_ent[p + 2], c3 = A.pu_ent[p + 3];
        float w0 = A.U0[(size_t)c0.x * 64 + lane];
        float w1 = A.U0[(size_t)c1.x * 64 + lane];
        float w2 = A.U0[(size_t)c2.x * 64 + lane];
        float w3 = A.U0[(size_t)c3.x * 64 + lane];
        acc = fmaf(__int_as_float(c0.y), w0, acc);
        acc = fmaf(__int_as_float(c1.y), w1, acc);
        acc = fmaf(__int_as_float(c2.y), w2, acc);
        acc = fmaf(__int_as_float(c3.y), w3, acc);
    }
    for (; p < e; ++p) {
        int2 c = A.pu_ent[p];
        acc = fmaf(__int_as_float(c.y), A.U0[(size_t)c.x * 64 + lane], acc);
    }
    float ss = acc * acc;
#pragma unroll
    for (int off = 32; off > 0; off >>= 1) ss += __shfl_xor(ss, off, 64);
    float d = fmaxf(sqrtf(ss), 1e-12f);
    float f = acc / d + A.P0[o] + A.P1[o];
    A.P3[o] = f;
    A.out_fp[o] = f;
}

// ================= D13: batch_users + loss =================
__global__ void batch_loss_kernel(MArgs A) {
    __shared__ float red[256];
    int tid = threadIdx.x;
    if ((int)blockIdx.x < 1024) {
        int lane = tid & 63;
        int b = blockIdx.x * 4 + (tid >> 6);
        int r = A.user_idx[b];
        float v = A.U0[(size_t)r * 64 + lane];
        float s = v * v;
#pragma unroll
        for (int off = 32; off > 0; off >>= 1) s += __shfl_xor(s, off, 64);
        float d = fmaxf(sqrtf(s), 1e-12f);
        A.out_bu[(size_t)b * 64 + lane] = v / d;
        return;
    }
    float acc = 0.0f;
    for (int i = tid; i < PN; i += 256) {
        float p = A.pos[i];
        acc += -logf(p / (A.rowsum[i] + 1e-8f) + 1e-8f);
        acc += -logf(p / (A.colsum[i] + 1e-8f) + 1e-8f);
    }
    red[tid] = acc;
    __syncthreads();
    for (int s = 128; s > 0; s >>= 1) {
        if (tid < s) red[tid] += red[tid + s];
        __syncthreads();
    }
    if (tid == 0) A.out_loss[0] = 0.5f * red[0] / (float)PN;
}

extern "C" void kernel_launch(void* const* d_in, const int* in_sizes, int n_in,
                              void* d_out, int out_size, void* d_ws, size_t ws_size,
                              hipStream_t stream) {
    (void)in_sizes; (void)n_in; (void)out_size;
    const int PD = PN * 64, UD = UN * 64;

    MArgs A;
    A.poi  = (const float*)d_in[0];
    A.uemb = (const float*)d_in[1];
    A.wgg  = (const float*)d_in[2];
    A.bgg  = (const float*)d_in[3];
    A.wgs  = (const float*)d_in[4];
    A.bgs  = (const float*)d_in[5];
    A.wgc  = (const float*)d_in[6];
    A.bgc  = (const float*)d_in[7];
    A.fw   = (const float*)d_in[8];
    A.fb   = (const float*)d_in[9];
    A.geo_vals = (const float*)d_in[10];
    A.src_vals = (const float*)d_in[11];
    A.tar_vals = (const float*)d_in[12];
    A.up_vals  = (const float*)d_in[13];
    A.pu_vals  = (const float*)d_in[14];
    A.geo_rows = (const int*)d_in[15];
    A.geo_cols = (const int*)d_in[16];
    A.src_rows = (const int*)d_in[17];
    A.src_cols = (const int*)d_in[18];
    A.tar_rows = (const int*)d_in[19];
    A.tar_cols = (const int*)d_in[20];
    A.up_rows  = (const int*)d_in[21];
    A.up_cols  = (const int*)d_in[22];
    A.pu_rows  = (const int*)d_in[23];
    A.pu_cols  = (const int*)d_in[24];
    A.user_idx = (const int*)d_in[25];

    float* F = (float*)d_ws;
    A.rowsum = F;
    A.colsum = A.rowsum + PN;
    A.pos    = A.colsum + PN;
    A.ngb    = (u16*)(F + 3 * PN);
    A.nsb    = A.ngb + PD;
    A.U0     = F + 3 * PN + PD;
    A.P0     = A.U0 + UD;
    A.P1     = A.P0 + PD;
    A.P2     = A.P1 + PD;
    A.P3     = A.P2 + PD;
    A.P4     = A.P3 + PD;
    int* M   = (int*)(A.P4 + PD);
    A.rp_geo = M;
    A.rp_tar = A.rp_geo + PN + 1;
    A.rp_src = A.rp_tar + PN + 1;
    A.rp_up  = A.rp_src + PN + 1;
    A.rp_pu  = A.rp_up + UN + 1;
    A.cnt    = M + RP_INTS;

    // pick shard count by workspace budget (deterministic across calls)
    size_t ent_bytes = (size_t)(NGE + NDE + NDE + NUE + NPUE) * 8;
    int S = 8;
    {
        size_t need8 = ((size_t)(3 * PN + PD + UD + 5 * PD) + RP_INTS + 8 * CNT_STRIDE) * 4 + ent_bytes;
        if (ws_size < need8) S = 1;
    }
    A.nshard = S;
    A.smask  = S - 1;
    int2* ents = (int2*)(A.cnt + S * CNT_STRIDE);
    A.geo_ent = ents;
    A.tar_ent = A.geo_ent + NGE;
    A.src_ent = A.tar_ent + NDE;
    A.up_ent  = A.src_ent + NDE;
    A.pu_ent  = A.up_ent + NUE;

    A.out_bu = (float*)d_out;
    A.out_fp = A.out_bu + (size_t)BN * 64;
    A.out_loss = A.out_fp + (size_t)PN * 64;

    const int NTOTB = (E4 + 255) / 256;            // 6875
    const int ZB = (3 * PN + S * CNT_STRIDE + 255) / 256;

    // D1: zero stats + sharded counters
    zero_kernel<<<ZB, 256, 0, stream>>>(A);
    // D2: sharded hist + geo/seq gates
    hist_gates_kernel<<<NTOTB + 5000, 256, 0, stream>>>(A);
    // D3: scans (1024 threads, batched shard loads)
    scan_kernel<<<5, 1024, 0, stream>>>(A);
    // D4: scatter int2 with sharded cursors
    scatter_kernel<<<NTOTB, 256, 0, stream>>>(A);
    // D5: geo1 || tar1
    spmm_step_kernel<<<5000, 256, 0, stream>>>(A, 0);
    // D6: geo2-final (ng) || s1
    spmm_step_kernel<<<5000, 256, 0, stream>>>(A, 1);
    // D7: tar2 || gate_col
    spmm_step_kernel<<<5000, 256, 0, stream>>>(A, 2);
    // D8: s2-final (ns)
    spmm_step_kernel<<<2500, 256, 0, stream>>>(A, 3);
    // D9: InfoNCE (MFMA) — standalone
    infonce_kernel<<<6241, 256, 0, stream>>>(A);
    // D10: spmm3(up) + fuse_users
    fuse_kernel<<<2000, 256, 0, stream>>>(A);
    // D11: pu spmm + fusion_out
    puout_kernel<<<2500, 256, 0, stream>>>(A);
    // D12: users_struct = up * fusion
    spmm_step_kernel<<<2000, 256, 0, stream>>>(A, 4);
    // D13: batch_users + loss
    batch_loss_kernel<<<1025, 256, 0, stream>>>(A);
}